// Round 12
// baseline (244.341 us; speedup 1.0000x reference)
//
#include <hip/hip_runtime.h>
#include <hip/hip_bf16.h>
#include <hip/hip_fp16.h>

// Problem constants (match reference)
#define TT 64
#define GN 1024
#define DK 128
#define NN (TT * GN)      // 65536
#define OUTC 131          // 3 + 128
#define TAU 5e-3f         // rescue threshold, 8.8 sigma of fp16-induced sim error

typedef _Float16 f16x8 __attribute__((ext_vector_type(8)));
typedef float    f32x4 __attribute__((ext_vector_type(4)));

// fp32 -> fp16 round-to-nearest-even, as raw 16 bits
__device__ __forceinline__ unsigned f2h(float f) {
    return (unsigned)__half_as_ushort(__float2half(f));
}

// fp32 -> fp16 rounded TOWARD +INF (conservative upper bound), as raw 16 bits
__device__ __forceinline__ unsigned hup(float x) {
    __half h = __float2half(x);                      // RTN
    unsigned short b = __half_as_ushort(h);
    if (__half2float(h) < x)                         // rounded down -> bump up
        b = (b & 0x8000) ? (unsigned short)(b - 1) : (unsigned short)(b + 1);
    return (unsigned)b;
}

// async global->LDS, 16 B per lane; LDS dest must be lane-contiguous (m104)
__device__ __forceinline__ void gload_lds16(const void* g, void* l) {
    __builtin_amdgcn_global_load_lds(
        (const __attribute__((address_space(1))) unsigned int*)g,
        (__attribute__((address_space(3))) unsigned int*)l, 16, 0, 0);
}

// ---------------------------------------------------------------------------
// Kernel 1: fused fp16 conversion + per-row reciprocal norms (fp64 accum).
// Also zeroes rcnt (block 0) and clen (first 256 blocks) - no memset dispatches.
// ---------------------------------------------------------------------------
__global__ void kconv(const float* __restrict__ feat, unsigned* __restrict__ fh,
                      float* __restrict__ rnf, double* __restrict__ rnd,
                      int* __restrict__ rcnt, int* __restrict__ clen) {
    if (blockIdx.x == 0 && threadIdx.x < 63) rcnt[threadIdx.x] = 0;
    if (blockIdx.x < 256) clen[blockIdx.x * 256 + threadIdx.x] = 0;
    int row  = blockIdx.x * 4 + (threadIdx.x >> 6);
    int lane = threadIdx.x & 63;
    const float* fr = feat + (size_t)row * DK;
    float2 v = *(const float2*)(fr + lane * 2);
    fh[(size_t)row * 64 + lane] = f2h(v.x) | (f2h(v.y) << 16);
    double s = (double)v.x * (double)v.x + (double)v.y * (double)v.y;
    #pragma unroll
    for (int off = 32; off > 0; off >>= 1)
        s += __shfl_down(s, off);
    if (lane == 0) {
        double m = sqrt(s);
        if (m < 1e-6) m = 1e-6;
        double r = 1.0 / m;
        rnd[row] = r;
        rnf[row] = (float)r;
    }
}

// ---------------------------------------------------------------------------
// Kernel 2 (R27): 16-WAVE blocks (1024 thr) = 2 A-halves x 8 col-groups of
// 16. R24 post-mortem: FETCH 9.8 MB (XCD remap fixed BW), Occ 17% = 2
// waves/SIMD, VALUBusy 35% - pure latency-bound. This doubles waves/SIMD to
// 4 within one block: per-wave private B dbuf halves to 2x4 KB (128 KB for
// 16 waves); rn moves from 64 VGPRs to a 4 KB LDS stage (ds_read, doesn't
// touch vmcnt -> R23's VMEM-free-loop invariant holds; staged in prologue
// behind the one barrier). Counted wait becomes vmcnt(4). Sketch becomes 32
// subsets (cg*4+lq; cols ntb*128+cg*16+lq*4+reg). Per-subset value order
// stays strictly n-ascending -> identical argmax/tie semantics.
// Operand-SWAPPED MFMA: D[m=B-col][n=A-row] so lane la indexes the sim ROW.
// ---------------------------------------------------------------------------
__global__ __launch_bounds__(1024, 4) void ksim(const unsigned* __restrict__ fh,
                                                const float* __restrict__ rnf,
                                                unsigned short* __restrict__ nxt16,
                                                int* __restrict__ rcnt,
                                                int* __restrict__ rlistT,
                                                uint2* __restrict__ skt) {
    __shared__ int   Tiles[16][2048];  // 128 KB: per-wave 2x4 KB dbuf
    __shared__ float rnS[1024];        // 4 KB: rn row, staged once
    __shared__ float mv1[1024];        // [128 rows][8 col-groups] merge
    __shared__ float mv2[1024];
    __shared__ int   mi1[1024];

    // XCD-aware remap (kept from R24): dispatch k -> work (k&7)*63 + (k>>3)
    int id = (blockIdx.x & 7) * 63 + (blockIdx.x >> 3);
    int t  = id >> 3;                  // 0..62
    int mt = id & 7;

    int tid  = threadIdx.x;            // 0..1023
    int wave = tid >> 6;               // 0..15
    int lane = tid & 63;
    int la = lane & 15;
    int lq = lane >> 4;
    int wr = (wave & 1) * 64;          // A-row half
    int cg = wave >> 1;                // col group 0..7
    int wc = cg * 16;                  // wave col offset (16 cols)

    const int* Ag = (const int*)fh + ((size_t)t * GN + mt * 128) * 64;
    const int* Bg = (const int*)fh + (size_t)(t + 1) * GN * 64;
    int* myT = &Tiles[wave][0];        // this wave's 2048-int private region

    // wave-private staging of B-slice (16 rows x 128 cols fp16 = 4 KB)
    // for nt-step ntb into private buffer b (0/1). 4 issues x 64 lanes x 16 B.
    #define STAGE_Q(ntb, b)                                                  \
        {                                                                    \
            const int* Bq = Bg + ((ntb) * 128 + cg * 16) * 64;               \
            _Pragma("unroll")                                                \
            for (int i = 0; i < 4; ++i) {                                    \
                int gidx = i * 64 + lane;                                    \
                int row = gidx >> 4, colG = (gidx & 15) ^ (row & 7);         \
                gload_lds16(Bq + row * 64 + colG * 4,                        \
                            myT + (b) * 1024 + gidx * 4);                    \
            }                                                                \
        }

    STAGE_Q(0, 0)                      // prologue: stage step-0 slice

    // rn row -> LDS once (waves 0..3 cover 4x256 floats); read via ds_read
    // in-loop (lgkmcnt, not vmcnt -> keeps the main loop VMEM-consumer-free)
    const float* rB = rnf + (size_t)(t + 1) * GN;
    if (wave < 4)
        gload_lds16(rB + wave * 256 + lane * 4, &rnS[wave * 256 + lane * 4]);

    // A fragments straight global->reg (64 B coalesced segments per (x,kc))
    f16x8 af[4][4];
    #pragma unroll
    for (int kc = 0; kc < 4; ++kc)
        #pragma unroll
        for (int x = 0; x < 4; ++x)
            af[kc][x] = __builtin_bit_cast(f16x8,
                *(const int4*)&Ag[(wr + x * 16 + la) * 64 + (kc * 4 + lq) * 4]);

    // running top-2: slot s=at -> row wr+at*16+la; cols wc+lq*4+reg
    float t1[4], t2[4]; int i1[4];
    #pragma unroll
    for (int s = 0; s < 4; ++s) { t1[s] = -3.4e38f; t2[s] = -3.4e38f; i1[s] = 0x7fffffff; }

    asm volatile("s_waitcnt vmcnt(0)" ::: "memory");   // own staging + A landed
    __syncthreads();                   // rnS (staged by waves 0-3) visible

    #pragma unroll                     // FULL unroll: static buffer indexing
    for (int ntb = 0; ntb < 8; ++ntb) {
        int cur = ntb & 1;
        if (ntb < 7) {                 // issue next slice, then counted wait:
            STAGE_Q(ntb + 1, cur ^ 1)  // 4 new loads in flight while the
            asm volatile("s_waitcnt vmcnt(4)" ::: "memory");  // prev 4 landed
        } else {
            asm volatile("s_waitcnt vmcnt(0)" ::: "memory");  // last buffer
        }

        f32x4 acc[4];
        #pragma unroll
        for (int at = 0; at < 4; ++at) acc[at] = (f32x4){0.f, 0.f, 0.f, 0.f};

        const int* Bt = myT + cur * 1024;   // private slice: 16 rows x 64 ints
        #pragma unroll
        for (int kc = 0; kc < 4; ++kc) {
            int sw = ((kc * 4 + lq) ^ (la & 7)) << 2;
            f16x8 bf = __builtin_bit_cast(f16x8, *(const int4*)&Bt[la * 64 + sw]);
            #pragma unroll
            for (int at = 0; at < 4; ++at)
                acc[at] = __builtin_amdgcn_mfma_f32_16x16x32_f16(
                    bf, af[kc][at], acc[at], 0, 0, 0);   // SWAPPED
        }

        // running top-2 update (ntb,reg ascending -> n ascending within the
        // lane's subset: strict > keeps the first argmax, matching jnp.argmax)
        f32x4 rn4 = *(const f32x4*)&rnS[ntb * 128 + wc + lq * 4];  // ds_read
        int nbase = ntb * 128 + wc + lq * 4;
        #pragma unroll
        for (int at = 0; at < 4; ++at) {
            #pragma unroll
            for (int reg = 0; reg < 4; ++reg) {
                float v = acc[at][reg] * rn4[reg];
                t2[at] = fmaxf(t2[at], fminf(v, t1[at]));   // med3(v,t1,t2)
                if (v > t1[at]) { t1[at] = v; i1[at] = nbase + reg; }
            }
        }
        // no barrier: buffer only re-staged by THIS wave after its own wait
    }
    #undef STAGE_Q

    // export per-lane subset sketch (32 subsets: cg*4+lq) BEFORE the butterfly
    // destroys it. 8 B/entry: t1 fp32 | (t2 fp16-up << 16) | i1 (10 bits).
    {
        uint2* sko = skt + (size_t)(cg * 4 + lq) * (63 * GN)
                         + (size_t)t * GN + mt * 128;
        #pragma unroll
        for (int s = 0; s < 4; ++s)
            sko[wr + s * 16 + la] = make_uint2(__float_as_uint(t1[s]),
                                               (hup(t2[s]) << 16) | (unsigned)i1[s]);
    }

    // butterfly top-2 merge over the 4 lq quads (same la = same row)
    #pragma unroll
    for (int m = 16; m <= 32; m <<= 1) {
        #pragma unroll
        for (int s = 0; s < 4; ++s) {
            float o1 = __shfl_xor(t1[s], m);
            float o2 = __shfl_xor(t2[s], m);
            int   oi = __shfl_xor(i1[s], m);
            bool take = (o1 > t1[s]) || (o1 == t1[s] && oi < i1[s]);
            float nt2 = take ? fmaxf(o2, t1[s]) : fmaxf(t2[s], o1);
            if (take) { t1[s] = o1; i1[s] = oi; }
            t2[s] = nt2;
        }
    }

    // cross-wave merge (8 col-groups) via the dedicated merge buffer
    if (lq == 0) {                     // lanes 0..15 hold merged rows
        #pragma unroll
        for (int s = 0; s < 4; ++s) {
            int idx = (wr + s * 16 + la) * 8 + cg;
            mv1[idx] = t1[s]; mv2[idx] = t2[s]; mi1[idx] = i1[s];
        }
    }
    __syncthreads();

    if (tid < 128) {                   // 8-way final merge + gap test
        int r8 = tid * 8;
        float best = mv1[r8], sec = mv2[r8];
        int bi = mi1[r8];
        #pragma unroll
        for (int c = 1; c < 8; ++c) {
            float v1 = mv1[r8 + c], v2 = mv2[r8 + c];
            int  ii = mi1[r8 + c];
            if (v1 > best || (v1 == best && ii < bi)) {
                sec = fmaxf(sec, fmaxf(best, v2)); best = v1; bi = ii;
            } else {
                sec = fmaxf(sec, v1);              // v2 <= v1 can't beat v1
            }
        }
        int grow = mt * 128 + tid;
        if (best - sec < TAU) {
            int p = atomicAdd(&rcnt[t], 1);
            rlistT[t * 1024 + p] = grow;
        } else {
            nxt16[t * GN + grow] = (unsigned short)bi;
        }
    }
}

// ---------------------------------------------------------------------------
// Kernel 4 (R27): candidate-set fp64 rescue over 32 subsets. Same verified
// logic as R21 (winner is a subset top-1 with t1 >= best-TAU, or hidden in a
// subset whose t2 >= best-TAU -> 32-col subset scan; t2 fp16-rounded-UP so
// the gate only widens the set). Lane-group g = lane>>2 handles subsets g
// and g+16 (two sketch entries); crowded scans run 16-candidate rounds.
// ---------------------------------------------------------------------------
__global__ __launch_bounds__(256) void krescue(const float* __restrict__ feat,
                                               const double* __restrict__ rnd,
                                               const int* __restrict__ rcnt,
                                               const int* __restrict__ rlistT,
                                               const uint2* __restrict__ skt,
                                               unsigned short* __restrict__ nxt16) {
    int bid = blockIdx.x;              // t*8 + p
    int t = bid >> 3;
    int nr = rcnt[t];
    if (nr == 0) return;
    int tid  = threadIdx.x;
    int wave = tid >> 6, lane = tid & 63;
    int wk = (bid & 7) * 4 + wave;     // worker 0..31 for this t
    int g  = lane >> 2;                // lane group 0..15
    int o  = (lane & 3) * 32;          // element offset within a 128-row

    const float*  Bt = feat + (size_t)(t + 1) * GN * DK;
    const double* rb = rnd + (size_t)(t + 1) * GN;

    for (int ri = wk; ri < nr; ri += 32) {
        int arow = rlistT[t * 1024 + ri];

        // A-slice for this lane (32 elems), reused for every candidate
        const float* ar = feat + ((size_t)t * GN + arow) * DK + o;
        double av[32];
        #pragma unroll
        for (int j = 0; j < 32; j += 4) {
            float4 a4 = *(const float4*)(ar + j);
            av[j] = a4.x; av[j + 1] = a4.y; av[j + 2] = a4.z; av[j + 3] = a4.w;
        }

        // this group's two subset sketch entries (subsets g and g+16)
        size_t gb = (size_t)t * GN + arow;
        uint2 e0 = skt[(size_t)g * (63 * GN) + gb];
        uint2 e1 = skt[(size_t)(g + 16) * (63 * GN) + gb];
        float t10  = __uint_as_float(e0.x);
        float t11  = __uint_as_float(e1.x);
        float t2u0 = __half2float(__ushort_as_half((unsigned short)(e0.y >> 16)));
        float t2u1 = __half2float(__ushort_as_half((unsigned short)(e1.y >> 16)));
        int   ic0  = (int)(e0.y & 1023u);
        int   ic1  = (int)(e1.y & 1023u);

        // global best over the 32 subsets via butterfly (exact fp32 t1)
        float best = fmaxf(t10, t11);
        best = fmaxf(best, __shfl_xor(best, 4));
        best = fmaxf(best, __shfl_xor(best, 8));
        best = fmaxf(best, __shfl_xor(best, 16));
        best = fmaxf(best, __shfl_xor(best, 32));
        float thr = best - TAU;

        double bv = -1.0e300; int bi = 0x7fffffff;

        // round 1: the (<=32) subset top-1 candidates, 16 at a time
        #pragma unroll
        for (int h = 0; h < 2; ++h) {
            int c = (h ? (t11 >= thr) : (t10 >= thr)) ? (h ? ic1 : ic0) : -1;
            double d = 0.0;
            if (c >= 0) {
                const float* br = Bt + (size_t)c * DK + o;
                #pragma unroll
                for (int jj = 0; jj < 32; jj += 4) {
                    float4 b4 = *(const float4*)(br + jj);
                    d = fma(av[jj],     (double)b4.x, d);
                    d = fma(av[jj + 1], (double)b4.y, d);
                    d = fma(av[jj + 2], (double)b4.z, d);
                    d = fma(av[jj + 3], (double)b4.w, d);
                }
            }
            d += __shfl_xor(d, 1); d += __shfl_xor(d, 2);
            if (c >= 0) {
                double v = d * rb[c];
                if (v > bv || (v == bv && c < bi)) { bv = v; bi = c; }
            }
        }

        // crowded subsets: 32-col scan, 16 candidates per round
        #pragma unroll 1
        for (int s = 0; s < 32; ++s) {
            float ey = __shfl((s < 16) ? t2u0 : t2u1, (s & 15) * 4);
            if (!(ey >= thr)) continue;
            int scg = s >> 2, slq = s & 3;     // subset s = scg*4 + slq
            #pragma unroll 1
            for (int r = 0; r < 2; ++r) {
                int j = r * 16 + g;            // 0..31 within subset s
                int c = (j >> 2) * 128 + scg * 16 + slq * 4 + (j & 3);
                const float* br = Bt + (size_t)c * DK + o;
                double d = 0.0;
                #pragma unroll
                for (int jj = 0; jj < 32; jj += 4) {
                    float4 b4 = *(const float4*)(br + jj);
                    d = fma(av[jj],     (double)b4.x, d);
                    d = fma(av[jj + 1], (double)b4.y, d);
                    d = fma(av[jj + 2], (double)b4.z, d);
                    d = fma(av[jj + 3], (double)b4.w, d);
                }
                d += __shfl_xor(d, 1); d += __shfl_xor(d, 2);
                double v = d * rb[c];
                if (v > bv || (v == bv && c < bi)) { bv = v; bi = c; }
            }
        }

        // cross-group merge (max, min-index tie) over the 16 lane groups
        #pragma unroll
        for (int m = 4; m <= 32; m <<= 1) {
            double ov = __shfl_xor(bv, m);
            int    oi = __shfl_xor(bi, m);
            if (ov > bv || (ov == bv && oi < bi)) { bv = ov; bi = oi; }
        }

        if (lane == 0) nxt16[t * GN + arow] = (unsigned short)bi;
    }
}

// ---------------------------------------------------------------------------
// Kernel 5 (R25, unchanged): chain propagation, ONE barrier per step.
// ---------------------------------------------------------------------------
__global__ __launch_bounds__(1024) void kgraph(const unsigned short* __restrict__ nxt16,
                                               int* __restrict__ chain_of) {
    __shared__ unsigned short ns[64 * 1024];   // 128 KB (row 63 unused pad)
    __shared__ int winner[2 * GN];             // 8 KB double-buffer
    int g = threadIdx.x;                       // 0..1023

    #pragma unroll
    for (int i = 0; i < 8; ++i)
        gload_lds16((const char*)nxt16 + ((size_t)i * 1024 + g) * 16,
                    (char*)ns + ((size_t)i * 1024 + g) * 16);

    winner[g] = 0x7fffffff;                    // init BOTH buffers once
    winner[GN + g] = 0x7fffffff;
    chain_of[g] = g;                           // group 0: identity
    __syncthreads();                           // drains the global_load_lds

    int mychain = g;
    for (int t = 0; t < TT - 1; ++t) {
        int* Wa = winner + (t & 1) * GN;
        int j = ns[t * GN + g];                // own slot (t,g)
        atomicMin(&Wa[j], mychain);            // vote
        __syncthreads();                       // all votes in
        int w = Wa[g];                         // own-slot read
        Wa[g] = 0x7fffffff;                    // own-slot reset for step t+2
        mychain = (w == 0x7fffffff) ? (((t + 1) << 10) | g) : w;
        ns[t * GN + g] = (unsigned short)mychain;   // recycle consumed slot
    }

    for (int t = 0; t < TT - 1; ++t)
        chain_of[(t + 1) * GN + g] = ns[t * GN + g];
}

// ---------------------------------------------------------------------------
// Kernel 6: chain lengths by owner count, 256 blocks (clen zeroed in kconv).
// ---------------------------------------------------------------------------
__global__ void kclen(const int* __restrict__ chain_of, int* __restrict__ clen) {
    int i = blockIdx.x * 256 + threadIdx.x;
    atomicAdd(&clen[chain_of[i]], 1);
}

// ---------------------------------------------------------------------------
// Kernel 7: per-block (1024-elem, coalesced) exclusive scan of kept lengths.
// ---------------------------------------------------------------------------
__global__ __launch_bounds__(1024) void kseg(const int* __restrict__ chain_of,
                                             const int* __restrict__ clen,
                                             const int* __restrict__ minp,
                                             int* __restrict__ oloc,
                                             int* __restrict__ partial) {
    __shared__ int ps[1024];
    int b = blockIdx.x, tid = threadIdx.x;
    int i = b * 1024 + tid;
    int ml = *minp;
    int cl = clen[i];
    int v = (chain_of[i] == i && cl >= ml) ? cl : 0;
    ps[tid] = v;
    __syncthreads();
    for (int off = 1; off < 1024; off <<= 1) {
        int add = (tid >= off) ? ps[tid - off] : 0;
        __syncthreads();
        ps[tid] += add;
        __syncthreads();
    }
    oloc[i] = ps[tid] - v;              // exclusive within block
    if (tid == 1023) partial[b] = ps[tid];
}

// ---------------------------------------------------------------------------
// Kernel 8: fused partial-scan + scatter + tail-zero.
// ---------------------------------------------------------------------------
__global__ __launch_bounds__(256) void kout(const float* __restrict__ coor,
                                            const float* __restrict__ feat,
                                            const int* __restrict__ chain_of,
                                            const int* __restrict__ clen,
                                            const int* __restrict__ oloc,
                                            const int* __restrict__ partial,
                                            const int* __restrict__ minp,
                                            float* __restrict__ out) {
    __shared__ int pb[64];
    __shared__ int stot;
    int tid = threadIdx.x;
    if (tid < 64) {
        int v = partial[tid];
        int acc = v;
        #pragma unroll
        for (int off = 1; off < 64; off <<= 1) {
            int o = __shfl_up(acc, off);
            if (tid >= off) acc += o;
        }
        pb[tid] = acc - v;
        if (tid == 63) stot = acc;
    }
    __syncthreads();

    int node = blockIdx.x * 4 + (tid >> 6);
    int lane = tid & 63;
    int s = chain_of[node];
    if (clen[s] >= *minp) {
        int row = oloc[s] + pb[s >> 10] + (node >> 10) - (s >> 10);
        float* orow = out + (size_t)row * OUTC;
        const float* f = feat + (size_t)node * DK;
        if (lane < 3) orow[lane] = coor[(size_t)node * 3 + lane];
        orow[3 + lane]  = f[lane];
        orow[67 + lane] = f[64 + lane];
    }

    int zrow = stot + blockIdx.x * 4 + (tid >> 6);
    if (zrow < NN) {
        float* orow = out + (size_t)zrow * OUTC;
        orow[lane] = 0.f;
        orow[64 + lane] = 0.f;
        if (lane < 3) orow[128 + lane] = 0.f;
    }
}

// ---------------------------------------------------------------------------
extern "C" void kernel_launch(void* const* d_in, const int* in_sizes, int n_in,
                              void* d_out, int out_size, void* d_ws, size_t ws_size,
                              hipStream_t stream) {
    const float* coor   = (const float*)d_in[0];   // [N,3]
    const float* feat   = (const float*)d_in[1];   // [N,128]
    const int*   minlen = (const int*)d_in[2];     // scalar
    float*       out    = (float*)d_out;           // [N,131] fp32

    char* ws = (char*)d_ws;
    double*         rnd      = (double*)(ws);                  // 512 KB
    float*          rnf      = (float*)(ws + 524288);          // 256 KB
    unsigned short* nxt16    = (unsigned short*)(ws + 786432); // 128 KB
    int*            chain_of = (int*)(ws + 917504);            // 256 KB
    int*            clen     = (int*)(ws + 1179648);           // 256 KB
    int*            oloc     = (int*)(ws + 1441792);           // 256 KB
    int*            rcnt     = (int*)(ws + 1703936);           // 63 ints
    int*            partial  = (int*)(ws + 1704192);           // 256 B
    int*            rlistT   = (int*)(ws + 1705216);           // 252 KB
    unsigned*       fh       = (unsigned*)(ws + 2097152);      // 16 MB
    // candidate sketch: 32 subsets x 63K rows x 8 B = 16.5 MB
    uint2*          skt      = (uint2*)(ws + 18874368);

    kconv<<<NN / 4, 256, 0, stream>>>(feat, fh, rnf, rnd, rcnt, clen);

    ksim<<<63 * 8, 1024, 0, stream>>>(fh, rnf, nxt16, rcnt, rlistT, skt);

    krescue<<<63 * 8, 256, 0, stream>>>(feat, rnd, rcnt, rlistT, skt, nxt16);

    kgraph<<<1, GN, 0, stream>>>(nxt16, chain_of);
    kclen<<<NN / 256, 256, 0, stream>>>(chain_of, clen);
    kseg<<<64, 1024, 0, stream>>>(chain_of, clen, minlen, oloc, partial);
    kout<<<NN / 4, 256, 0, stream>>>(coor, feat, chain_of, clen, oloc, partial,
                                     minlen, out);
}

// Round 13
// 188.161 us; speedup vs baseline: 1.2986x; 1.2986x over previous
//
#include <hip/hip_runtime.h>
#include <hip/hip_bf16.h>
#include <hip/hip_fp16.h>

// Problem constants (match reference)
#define TT 64
#define GN 1024
#define DK 128
#define NN (TT * GN)      // 65536
#define OUTC 131          // 3 + 128
#define TAU 5e-3f         // rescue threshold, 8.8 sigma of fp16-induced sim error

typedef _Float16 f16x8 __attribute__((ext_vector_type(8)));
typedef float    f32x4 __attribute__((ext_vector_type(4)));

// fp32 -> fp16 round-to-nearest-even, as raw 16 bits
__device__ __forceinline__ unsigned f2h(float f) {
    return (unsigned)__half_as_ushort(__float2half(f));
}

// fp32 -> fp16 rounded TOWARD +INF (conservative upper bound), as raw 16 bits
__device__ __forceinline__ unsigned hup(float x) {
    __half h = __float2half(x);                      // RTN
    unsigned short b = __half_as_ushort(h);
    if (__half2float(h) < x)                         // rounded down -> bump up
        b = (b & 0x8000) ? (unsigned short)(b - 1) : (unsigned short)(b + 1);
    return (unsigned)b;
}

// async global->LDS, 16 B per lane; LDS dest must be lane-contiguous (m104)
__device__ __forceinline__ void gload_lds16(const void* g, void* l) {
    __builtin_amdgcn_global_load_lds(
        (const __attribute__((address_space(1))) unsigned int*)g,
        (__attribute__((address_space(3))) unsigned int*)l, 16, 0, 0);
}

// ---------------------------------------------------------------------------
// Kernel 1: fused fp16 conversion + per-row reciprocal norms (fp64 accum).
// Also zeroes rcnt (block 0) and clen (first 256 blocks) - no memset dispatches.
// ---------------------------------------------------------------------------
__global__ void kconv(const float* __restrict__ feat, unsigned* __restrict__ fh,
                      float* __restrict__ rnf, double* __restrict__ rnd,
                      int* __restrict__ rcnt, int* __restrict__ clen) {
    if (blockIdx.x == 0 && threadIdx.x < 63) rcnt[threadIdx.x] = 0;
    if (blockIdx.x < 256) clen[blockIdx.x * 256 + threadIdx.x] = 0;
    int row  = blockIdx.x * 4 + (threadIdx.x >> 6);
    int lane = threadIdx.x & 63;
    const float* fr = feat + (size_t)row * DK;
    float2 v = *(const float2*)(fr + lane * 2);
    fh[(size_t)row * 64 + lane] = f2h(v.x) | (f2h(v.y) << 16);
    double s = (double)v.x * (double)v.x + (double)v.y * (double)v.y;
    #pragma unroll
    for (int off = 32; off > 0; off >>= 1)
        s += __shfl_down(s, off);
    if (lane == 0) {
        double m = sqrt(s);
        if (m < 1e-6) m = 1e-6;
        double r = 1.0 / m;
        rnd[row] = r;
        rnf[row] = (float)r;
    }
}

// ---------------------------------------------------------------------------
// Kernel 2 (R24 - REVERTED to the 188.5 us best after R12's 16-wave attempt
// spilled: launch_bounds(1024,4) capped VGPR at 64 vs ~130 live -> 187 MB
// scratch writes, 2.5x regression. 16 waves needs <=128 VGPR, kernel wants
// ~130 - a knife-edge not worth another round. This 512-thread config is
// the verified optimum: XCD-aware remap (FETCH 68.9->9.8 MB), wave-private
// 2x8 KB dbuf, VMEM-free main loop with counted vmcnt(8), hoisted rnv.
// Operand-SWAPPED MFMA: D[m=B-col][n=A-row] so lane la indexes the sim ROW.
// ---------------------------------------------------------------------------
__global__ __launch_bounds__(512) void ksim(const unsigned* __restrict__ fh,
                                            const float* __restrict__ rnf,
                                            unsigned short* __restrict__ nxt16,
                                            int* __restrict__ rcnt,
                                            int* __restrict__ rlistT,
                                            uint2* __restrict__ skt) {
    __shared__ int Tiles[8][4096];     // 128 KB: per-wave 2x8 KB dbuf
    __shared__ float mv1[512];         // [128 rows][4 col-groups] merge
    __shared__ float mv2[512];
    __shared__ int   mi1[512];

    // XCD-aware remap: dispatch id k -> work id (k&7)*63 + (k>>3)
    int id = (blockIdx.x & 7) * 63 + (blockIdx.x >> 3);
    int t  = id >> 3;                  // 0..62
    int mt = id & 7;

    int tid  = threadIdx.x;            // 0..511
    int wave = tid >> 6;               // 0..7
    int lane = tid & 63;
    int la = lane & 15;
    int lq = lane >> 4;
    int wr = (wave & 1) * 64;          // wave row offset
    int cg = wave >> 1;                // col group 0..3
    int wc = cg * 32;                  // wave col offset (within 128-chunk)

    const int* Ag = (const int*)fh + ((size_t)t * GN + mt * 128) * 64;
    const int* Bg = (const int*)fh + (size_t)(t + 1) * GN * 64;
    int* myT = &Tiles[wave][0];        // this wave's 4096-int private region

    // wave-private staging of B-quarter (32 rows x 128 cols fp16 = 8 KB)
    // for nt-step ntb into private buffer b (0/1). 8 issues x 64 lanes x 16 B.
    #define STAGE_Q(ntb, b)                                                  \
        {                                                                    \
            const int* Bq = Bg + ((ntb) * 128 + cg * 32) * 64;               \
            _Pragma("unroll")                                                \
            for (int i = 0; i < 8; ++i) {                                    \
                int gidx = i * 64 + lane;                                    \
                int row = gidx >> 4, colG = (gidx & 15) ^ (row & 7);         \
                gload_lds16(Bq + row * 64 + colG * 4,                        \
                            myT + (b) * 2048 + gidx * 4);                    \
            }                                                                \
        }

    STAGE_Q(0, 0)                      // prologue: stage step-0 quarter

    const float* rB = rnf + (size_t)(t + 1) * GN;

    // ALL rn loads hoisted: 16 float4/lane, statically indexed (full unroll)
    f32x4 rnv[8][2];
    #pragma unroll
    for (int ntb = 0; ntb < 8; ++ntb)
        #pragma unroll
        for (int ct = 0; ct < 2; ++ct)
            rnv[ntb][ct] = *(const f32x4*)&rB[ntb * 128 + wc + ct * 16 + lq * 4];

    // A fragments straight global->reg (64 B coalesced segments per (x,kc))
    f16x8 af[4][4];
    #pragma unroll
    for (int kc = 0; kc < 4; ++kc)
        #pragma unroll
        for (int x = 0; x < 4; ++x)
            af[kc][x] = __builtin_bit_cast(f16x8,
                *(const int4*)&Ag[(wr + x * 16 + la) * 64 + (kc * 4 + lq) * 4]);

    // running top-2: slot s=at -> row wr+at*16+la; cols wc+ct*16+lq*4+reg
    float t1[4], t2[4]; int i1[4];
    #pragma unroll
    for (int s = 0; s < 4; ++s) { t1[s] = -3.4e38f; t2[s] = -3.4e38f; i1[s] = 0x7fffffff; }

    asm volatile("s_waitcnt vmcnt(0)" ::: "memory");   // buf0 + rn + A landed

    #pragma unroll                     // FULL unroll: static rnv/buffer indexing
    for (int ntb = 0; ntb < 8; ++ntb) {
        int cur = ntb & 1;
        if (ntb < 7) {                 // issue next quarter, then counted wait:
            STAGE_Q(ntb + 1, cur ^ 1)  // the 8 new loads stay in flight while
            asm volatile("s_waitcnt vmcnt(8)" ::: "memory");  // prev staging done
        } else {
            asm volatile("s_waitcnt vmcnt(0)" ::: "memory");  // last buffer done
        }

        f32x4 acc[4][2];
        #pragma unroll
        for (int at = 0; at < 4; ++at)
            #pragma unroll
            for (int ct = 0; ct < 2; ++ct) acc[at][ct] = (f32x4){0.f, 0.f, 0.f, 0.f};

        const int* Bt = myT + cur * 2048;   // private quarter: 32 rows x 64 ints
        #pragma unroll
        for (int kc = 0; kc < 4; ++kc) {
            int sw = ((kc * 4 + lq) ^ (la & 7)) << 2;
            f16x8 bf[2];
            #pragma unroll
            for (int x = 0; x < 2; ++x)
                bf[x] = __builtin_bit_cast(f16x8, *(const int4*)&Bt[(x * 16 + la) * 64 + sw]);
            #pragma unroll
            for (int at = 0; at < 4; ++at)
                #pragma unroll
                for (int ct = 0; ct < 2; ++ct)
                    acc[at][ct] = __builtin_amdgcn_mfma_f32_16x16x32_f16(
                        bf[ct], af[kc][at], acc[at][ct], 0, 0, 0);   // SWAPPED
        }

        // running top-2 update (ntb,ct,reg ascending -> n ascending within the
        // lane's subset: strict > keeps the first argmax, matching jnp.argmax)
        #pragma unroll
        for (int ct = 0; ct < 2; ++ct) {
            int nbase = ntb * 128 + wc + ct * 16 + lq * 4;
            #pragma unroll
            for (int at = 0; at < 4; ++at) {
                #pragma unroll
                for (int reg = 0; reg < 4; ++reg) {
                    float v = acc[at][ct][reg] * rnv[ntb][ct][reg];
                    t2[at] = fmaxf(t2[at], fminf(v, t1[at]));   // med3(v,t1,t2)
                    if (v > t1[at]) { t1[at] = v; i1[at] = nbase + reg; }
                }
            }
        }
        // no barrier: the buffer we just read is only re-staged by THIS wave
        // on the next iteration, after its own counted wait
    }
    #undef STAGE_Q

    // export per-lane subset sketch (16 subsets: cg*4+lq) BEFORE the butterfly
    // destroys it. 8 B/entry: t1 fp32 | (t2 fp16-up << 16) | i1 (10 bits).
    {
        uint2* sko = skt + (size_t)(cg * 4 + lq) * (63 * GN)
                         + (size_t)t * GN + mt * 128;
        #pragma unroll
        for (int s = 0; s < 4; ++s)
            sko[wr + s * 16 + la] = make_uint2(__float_as_uint(t1[s]),
                                               (hup(t2[s]) << 16) | (unsigned)i1[s]);
    }

    // butterfly top-2 merge over the 4 lq quads (same la = same row)
    #pragma unroll
    for (int m = 16; m <= 32; m <<= 1) {
        #pragma unroll
        for (int s = 0; s < 4; ++s) {
            float o1 = __shfl_xor(t1[s], m);
            float o2 = __shfl_xor(t2[s], m);
            int   oi = __shfl_xor(i1[s], m);
            bool take = (o1 > t1[s]) || (o1 == t1[s] && oi < i1[s]);
            float nt2 = take ? fmaxf(o2, t1[s]) : fmaxf(t2[s], o1);
            if (take) { t1[s] = o1; i1[s] = oi; }
            t2[s] = nt2;
        }
    }

    // cross-wave merge (4 col-groups) via the dedicated merge buffer
    if (lq == 0) {                     // lanes 0..15 hold merged rows
        #pragma unroll
        for (int s = 0; s < 4; ++s) {
            int idx = (wr + s * 16 + la) * 4 + cg;
            mv1[idx] = t1[s]; mv2[idx] = t2[s]; mi1[idx] = i1[s];
        }
    }
    __syncthreads();

    if (tid < 128) {                   // 4-way final merge + gap test
        int r4 = tid * 4;
        float best = mv1[r4], sec = mv2[r4];
        int bi = mi1[r4];
        #pragma unroll
        for (int c = 1; c < 4; ++c) {
            float v1 = mv1[r4 + c], v2 = mv2[r4 + c];
            int  ii = mi1[r4 + c];
            if (v1 > best || (v1 == best && ii < bi)) {
                sec = fmaxf(sec, fmaxf(best, v2)); best = v1; bi = ii;
            } else {
                sec = fmaxf(sec, v1);              // v2 <= v1 can't beat v1
            }
        }
        int grow = mt * 128 + tid;
        if (best - sec < TAU) {
            int p = atomicAdd(&rcnt[t], 1);
            rlistT[t * 1024 + p] = grow;
        } else {
            nxt16[t * GN + grow] = (unsigned short)bi;
        }
    }
}

// ---------------------------------------------------------------------------
// Kernel 4 (R21, unchanged): candidate-set fp64 rescue over 16 subsets.
// Winner is a subset top-1 with t1 >= best-TAU, or hidden in a subset whose
// t2 >= best-TAU -> 64-col subset scan; t2 fp16-rounded-UP only widens the
// set. 16 quad-lane candidate groups; one 5-step cross-merge per row.
// ---------------------------------------------------------------------------
__global__ __launch_bounds__(256) void krescue(const float* __restrict__ feat,
                                               const double* __restrict__ rnd,
                                               const int* __restrict__ rcnt,
                                               const int* __restrict__ rlistT,
                                               const uint2* __restrict__ skt,
                                               unsigned short* __restrict__ nxt16) {
    int bid = blockIdx.x;              // t*8 + p
    int t = bid >> 3;
    int nr = rcnt[t];
    if (nr == 0) return;
    int tid  = threadIdx.x;
    int wave = tid >> 6, lane = tid & 63;
    int wk = (bid & 7) * 4 + wave;     // worker 0..31 for this t
    int g  = lane >> 2;                // candidate/subset group 0..15
    int o  = (lane & 3) * 32;          // element offset within a 128-row

    const float*  Bt = feat + (size_t)(t + 1) * GN * DK;
    const double* rb = rnd + (size_t)(t + 1) * GN;

    for (int ri = wk; ri < nr; ri += 32) {
        int arow = rlistT[t * 1024 + ri];

        // A-slice for this lane (32 elems), reused for every candidate
        const float* ar = feat + ((size_t)t * GN + arow) * DK + o;
        double av[32];
        #pragma unroll
        for (int j = 0; j < 32; j += 4) {
            float4 a4 = *(const float4*)(ar + j);
            av[j] = a4.x; av[j + 1] = a4.y; av[j + 2] = a4.z; av[j + 3] = a4.w;
        }

        // lane group's subset sketch entry (4 lanes share -> broadcast)
        size_t gb = (size_t)t * GN + arow;
        uint2 eg = skt[(size_t)g * (63 * GN) + gb];
        float t1  = __uint_as_float(eg.x);
        float t2u = __half2float(__ushort_as_half((unsigned short)(eg.y >> 16)));
        int   ic  = (int)(eg.y & 1023u);

        // global best over the 16 subsets via butterfly (exact fp32 t1)
        float best = t1;
        best = fmaxf(best, __shfl_xor(best, 4));
        best = fmaxf(best, __shfl_xor(best, 8));
        best = fmaxf(best, __shfl_xor(best, 16));
        best = fmaxf(best, __shfl_xor(best, 32));
        float thr = best - TAU;

        double bv = -1.0e300; int bi = 0x7fffffff;

        // round 1: up to 16 subset top-1 candidates, all in parallel
        {
            int c = (t1 >= thr) ? ic : -1;
            double d = 0.0;
            if (c >= 0) {
                const float* br = Bt + (size_t)c * DK + o;
                #pragma unroll
                for (int jj = 0; jj < 32; jj += 4) {
                    float4 b4 = *(const float4*)(br + jj);
                    d = fma(av[jj],     (double)b4.x, d);
                    d = fma(av[jj + 1], (double)b4.y, d);
                    d = fma(av[jj + 2], (double)b4.z, d);
                    d = fma(av[jj + 3], (double)b4.w, d);
                }
            }
            d += __shfl_xor(d, 1); d += __shfl_xor(d, 2);
            if (c >= 0) {
                double v = d * rb[c];
                if (v > bv || (v == bv && c < bi)) { bv = v; bi = c; }
            }
        }

        // crowded subsets: 64-col scan, 16 candidates per round
        #pragma unroll 1
        for (int s = 0; s < 16; ++s) {
            float ey = __shfl(t2u, s * 4);     // subset s's top-2 (upper bound)
            if (!(ey >= thr)) continue;
            int cgs = s >> 2, lqs = s & 3;
            #pragma unroll 1
            for (int r = 0; r < 4; ++r) {
                int j = r * 16 + g;            // 0..63 within subset s
                int c = (j >> 3) * 128 + cgs * 32 + ((j >> 2) & 1) * 16
                      + lqs * 4 + (j & 3);
                const float* br = Bt + (size_t)c * DK + o;
                double d = 0.0;
                #pragma unroll
                for (int jj = 0; jj < 32; jj += 4) {
                    float4 b4 = *(const float4*)(br + jj);
                    d = fma(av[jj],     (double)b4.x, d);
                    d = fma(av[jj + 1], (double)b4.y, d);
                    d = fma(av[jj + 2], (double)b4.z, d);
                    d = fma(av[jj + 3], (double)b4.w, d);
                }
                d += __shfl_xor(d, 1); d += __shfl_xor(d, 2);
                double v = d * rb[c];
                if (v > bv || (v == bv && c < bi)) { bv = v; bi = c; }
            }
        }

        // cross-group merge (max, min-index tie) over the 16 lane groups
        #pragma unroll
        for (int m = 4; m <= 32; m <<= 1) {
            double ov = __shfl_xor(bv, m);
            int    oi = __shfl_xor(bi, m);
            if (ov > bv || (ov == bv && oi < bi)) { bv = ov; bi = oi; }
        }

        if (lane == 0) nxt16[t * GN + arow] = (unsigned short)bi;
    }
}

// ---------------------------------------------------------------------------
// Kernel 5 (R25, unchanged): chain propagation, ONE barrier per step.
// Vote -> barrier -> own-slot read + own-slot reset -> update. The reset of
// Wa[g] (for reuse at step t+2) is separated from step t+2's votes by
// barrier_{t+1}; each thread reads only its own slot, so no cross-thread
// hazard. Both winner buffers INF-initialized once. Same winner semantics.
// ---------------------------------------------------------------------------
__global__ __launch_bounds__(1024) void kgraph(const unsigned short* __restrict__ nxt16,
                                               int* __restrict__ chain_of) {
    __shared__ unsigned short ns[64 * 1024];   // 128 KB (row 63 unused pad)
    __shared__ int winner[2 * GN];             // 8 KB double-buffer
    int g = threadIdx.x;                       // 0..1023

    #pragma unroll
    for (int i = 0; i < 8; ++i)
        gload_lds16((const char*)nxt16 + ((size_t)i * 1024 + g) * 16,
                    (char*)ns + ((size_t)i * 1024 + g) * 16);

    winner[g] = 0x7fffffff;                    // init BOTH buffers once
    winner[GN + g] = 0x7fffffff;
    chain_of[g] = g;                           // group 0: identity
    __syncthreads();                           // drains the global_load_lds

    int mychain = g;
    for (int t = 0; t < TT - 1; ++t) {
        int* Wa = winner + (t & 1) * GN;
        int j = ns[t * GN + g];                // own slot (t,g)
        atomicMin(&Wa[j], mychain);            // vote
        __syncthreads();                       // all votes in
        int w = Wa[g];                         // own-slot read
        Wa[g] = 0x7fffffff;                    // own-slot reset for step t+2
        mychain = (w == 0x7fffffff) ? (((t + 1) << 10) | g) : w;
        ns[t * GN + g] = (unsigned short)mychain;   // recycle consumed slot
    }

    for (int t = 0; t < TT - 1; ++t)
        chain_of[(t + 1) * GN + g] = ns[t * GN + g];
}

// ---------------------------------------------------------------------------
// Kernel 6: chain lengths by owner count, 256 blocks (clen zeroed in kconv).
// ---------------------------------------------------------------------------
__global__ void kclen(const int* __restrict__ chain_of, int* __restrict__ clen) {
    int i = blockIdx.x * 256 + threadIdx.x;
    atomicAdd(&clen[chain_of[i]], 1);
}

// ---------------------------------------------------------------------------
// Kernel 7: per-block (1024-elem, coalesced) exclusive scan of kept lengths.
// ---------------------------------------------------------------------------
__global__ __launch_bounds__(1024) void kseg(const int* __restrict__ chain_of,
                                             const int* __restrict__ clen,
                                             const int* __restrict__ minp,
                                             int* __restrict__ oloc,
                                             int* __restrict__ partial) {
    __shared__ int ps[1024];
    int b = blockIdx.x, tid = threadIdx.x;
    int i = b * 1024 + tid;
    int ml = *minp;
    int cl = clen[i];
    int v = (chain_of[i] == i && cl >= ml) ? cl : 0;
    ps[tid] = v;
    __syncthreads();
    for (int off = 1; off < 1024; off <<= 1) {
        int add = (tid >= off) ? ps[tid - off] : 0;
        __syncthreads();
        ps[tid] += add;
        __syncthreads();
    }
    oloc[i] = ps[tid] - v;              // exclusive within block
    if (tid == 1023) partial[b] = ps[tid];
}

// ---------------------------------------------------------------------------
// Kernel 8: fused partial-scan + scatter + tail-zero.
// ---------------------------------------------------------------------------
__global__ __launch_bounds__(256) void kout(const float* __restrict__ coor,
                                            const float* __restrict__ feat,
                                            const int* __restrict__ chain_of,
                                            const int* __restrict__ clen,
                                            const int* __restrict__ oloc,
                                            const int* __restrict__ partial,
                                            const int* __restrict__ minp,
                                            float* __restrict__ out) {
    __shared__ int pb[64];
    __shared__ int stot;
    int tid = threadIdx.x;
    if (tid < 64) {
        int v = partial[tid];
        int acc = v;
        #pragma unroll
        for (int off = 1; off < 64; off <<= 1) {
            int o = __shfl_up(acc, off);
            if (tid >= off) acc += o;
        }
        pb[tid] = acc - v;
        if (tid == 63) stot = acc;
    }
    __syncthreads();

    int node = blockIdx.x * 4 + (tid >> 6);
    int lane = tid & 63;
    int s = chain_of[node];
    if (clen[s] >= *minp) {
        int row = oloc[s] + pb[s >> 10] + (node >> 10) - (s >> 10);
        float* orow = out + (size_t)row * OUTC;
        const float* f = feat + (size_t)node * DK;
        if (lane < 3) orow[lane] = coor[(size_t)node * 3 + lane];
        orow[3 + lane]  = f[lane];
        orow[67 + lane] = f[64 + lane];
    }

    int zrow = stot + blockIdx.x * 4 + (tid >> 6);
    if (zrow < NN) {
        float* orow = out + (size_t)zrow * OUTC;
        orow[lane] = 0.f;
        orow[64 + lane] = 0.f;
        if (lane < 3) orow[128 + lane] = 0.f;
    }
}

// ---------------------------------------------------------------------------
extern "C" void kernel_launch(void* const* d_in, const int* in_sizes, int n_in,
                              void* d_out, int out_size, void* d_ws, size_t ws_size,
                              hipStream_t stream) {
    const float* coor   = (const float*)d_in[0];   // [N,3]
    const float* feat   = (const float*)d_in[1];   // [N,128]
    const int*   minlen = (const int*)d_in[2];     // scalar
    float*       out    = (float*)d_out;           // [N,131] fp32

    char* ws = (char*)d_ws;
    double*         rnd      = (double*)(ws);                  // 512 KB
    float*          rnf      = (float*)(ws + 524288);          // 256 KB
    unsigned short* nxt16    = (unsigned short*)(ws + 786432); // 128 KB
    int*            chain_of = (int*)(ws + 917504);            // 256 KB
    int*            clen     = (int*)(ws + 1179648);           // 256 KB
    int*            oloc     = (int*)(ws + 1441792);           // 256 KB
    int*            rcnt     = (int*)(ws + 1703936);           // 63 ints
    int*            partial  = (int*)(ws + 1704192);           // 256 B
    int*            rlistT   = (int*)(ws + 1705216);           // 252 KB
    unsigned*       fh       = (unsigned*)(ws + 2097152);      // 16 MB
    // candidate sketch: 16 subsets x 63K rows x 8 B = 8.25 MB
    uint2*          skt      = (uint2*)(ws + 18874368);

    kconv<<<NN / 4, 256, 0, stream>>>(feat, fh, rnf, rnd, rcnt, clen);

    ksim<<<63 * 8, 512, 0, stream>>>(fh, rnf, nxt16, rcnt, rlistT, skt);

    krescue<<<63 * 8, 256, 0, stream>>>(feat, rnd, rcnt, rlistT, skt, nxt16);

    kgraph<<<1, GN, 0, stream>>>(nxt16, chain_of);
    kclen<<<NN / 256, 256, 0, stream>>>(chain_of, clen);
    kseg<<<64, 1024, 0, stream>>>(chain_of, clen, minlen, oloc, partial);
    kout<<<NN / 4, 256, 0, stream>>>(coor, feat, chain_of, clen, oloc, partial,
                                     minlen, out);
}